// Round 2
// baseline (11007.469 us; speedup 1.0000x reference)
//
#include <hip/hip_runtime.h>
#include <math.h>

#define HH   150        // hidden per direction
#define G4   600        // 4*H
#define DD   300        // embedding dim
#define CLS  7
#define SS   1024       // sentences
#define WW   128        // words per sentence
#define KCAT 450        // D + H
#define KPAD 456        // padded (456*4B % 16 == 0, 456/4 = 114 chunks)
#define K2PAD 152       // H padded to float4 multiple

__device__ __forceinline__ float sigf(float x) {
    return 1.0f / (1.0f + exp2f(-1.44269504088896341f * x));
}
__device__ __forceinline__ float tanh_f(float x) {
    return 2.0f / (1.0f + exp2f(-2.88539008177792681f * x)) - 1.0f;
}

// ---------------- weight packing ----------------
// Wcat: [2][600][KPAD] = [Wih row (300) | Whh row (150) | zeros(6)]
__global__ void pack1_kernel(const float* __restrict__ Wih_f, const float* __restrict__ Whh_f,
                             const float* __restrict__ Wih_b, const float* __restrict__ Whh_b,
                             float* __restrict__ Wcat) {
    int idx = blockIdx.x * 256 + threadIdx.x;
    const int total = 2 * G4 * KPAD;
    if (idx >= total) return;
    int k = idx % KPAD;
    int r = idx / KPAD;
    int o = r % G4;
    int dir = r / G4;
    const float* Wih = dir ? Wih_b : Wih_f;
    const float* Whh = dir ? Whh_b : Whh_f;
    float v = 0.0f;
    if (k < DD) v = Wih[o * DD + k];
    else if (k < KCAT) v = Whh[o * HH + (k - DD)];
    Wcat[idx] = v;
}

// W2cat: [2][600][K2PAD] = [Whh2 row (150) | zeros(2)]
__global__ void pack2_kernel(const float* __restrict__ Whh_f2, const float* __restrict__ Whh_b2,
                             float* __restrict__ W2cat) {
    int idx = blockIdx.x * 256 + threadIdx.x;
    const int total = 2 * G4 * K2PAD;
    if (idx >= total) return;
    int k = idx % K2PAD;
    int r = idx / K2PAD;
    int o = r % G4;
    int dir = r / G4;
    const float* Whh = dir ? Whh_b2 : Whh_f2;
    float v = (k < HH) ? Whh[o * HH + k] : 0.0f;
    W2cat[idx] = v;
}

// ---------------- word-level BiLSTM (stage 1) ----------------
// grid 256 = 128 sentence-blocks x 2 dirs; block 640.
// Each WG: 8 sentences, one direction, 128 fused (input-proj + recurrent) steps,
// running max of h -> sent_emb half.
__global__ __launch_bounds__(640, 1) void word_lstm_kernel(
    const float* __restrict__ x,        // [S][W][D]
    const float* __restrict__ Wcat,     // [2][600][KPAD]
    const float* __restrict__ bih_f, const float* __restrict__ bhh_f,
    const float* __restrict__ bih_b, const float* __restrict__ bhh_b,
    float* __restrict__ sent_emb)       // [S][300]
{
    __shared__ __align__(16) float xh[8][KPAD];   // [x(300) | h(150) | pad0(6)]
    __shared__ __align__(16) float g[8][G4];
    __shared__ __align__(16) float cst[8][HH];
    __shared__ __align__(16) float hmax[8][HH];

    const int tid = threadIdx.x;
    const int dir = blockIdx.x & 1;
    const int sb  = blockIdx.x >> 1;
    const int s0  = sb * 8;

    for (int i = tid; i < 8 * KPAD; i += 640) ((float*)xh)[i] = 0.0f;  // h0=0, pads=0
    for (int i = tid; i < 8 * HH; i += 640) {
        ((float*)cst)[i] = 0.0f;
        ((float*)hmax)[i] = -INFINITY;
    }

    const float4* wr4 = nullptr;
    float bias = 0.0f;
    if (tid < G4) {
        wr4 = (const float4*)(Wcat + ((size_t)dir * G4 + tid) * KPAD);
        bias = dir ? (bih_b[tid] + bhh_b[tid]) : (bih_f[tid] + bhh_f[tid]);
    }

    // prologue: stage x for first time index
    {
        int t0 = (dir == 0) ? 0 : (WW - 1);
        __syncthreads();
        for (int i = tid; i < 8 * DD; i += 640) {
            int s = i / DD, d = i - s * DD;
            xh[s][d] = x[((size_t)(s0 + s) * WW + t0) * DD + d];
        }
    }
    __syncthreads();

    for (int st = 0; st < WW; ++st) {
        const int tt = (dir == 0) ? st : (WW - 1 - st);
        const int tn = (dir == 0) ? (tt + 1) : (tt - 1);
        const bool has_next = (st + 1 < WW);

        // prefetch next x into registers (static indexing; 2400 vals over 640 threads)
        float pf0 = 0.f, pf1 = 0.f, pf2 = 0.f, pf3 = 0.f;
        if (has_next) {
            int i0 = tid, i1 = tid + 640, i2 = tid + 1280, i3 = tid + 1920;
            int sA = i0 / DD, dA = i0 - sA * DD;
            int sB = i1 / DD, dB = i1 - sB * DD;
            int sC = i2 / DD, dC = i2 - sC * DD;
            pf0 = x[((size_t)(s0 + sA) * WW + tn) * DD + dA];
            pf1 = x[((size_t)(s0 + sB) * WW + tn) * DD + dB];
            pf2 = x[((size_t)(s0 + sC) * WW + tn) * DD + dC];
            if (i3 < 8 * DD) {
                int sD = i3 / DD, dD = i3 - sD * DD;
                pf3 = x[((size_t)(s0 + sD) * WW + tn) * DD + dD];
            }
        }

        // dot phase: g[s][o] = bias + [x|h] . Wcat[o]
        if (tid < G4) {
            float acc[8];
            #pragma unroll
            for (int s = 0; s < 8; ++s) acc[s] = bias;
            #pragma unroll 2
            for (int kc = 0; kc < KPAD / 4; ++kc) {
                float4 w4 = wr4[kc];
                #pragma unroll
                for (int s = 0; s < 8; ++s) {
                    float4 xv = *((const float4*)&xh[s][kc * 4]);
                    acc[s] = fmaf(w4.x, xv.x, acc[s]);
                    acc[s] = fmaf(w4.y, xv.y, acc[s]);
                    acc[s] = fmaf(w4.z, xv.z, acc[s]);
                    acc[s] = fmaf(w4.w, xv.w, acc[s]);
                }
            }
            #pragma unroll
            for (int s = 0; s < 8; ++s) g[s][tid] = acc[s];
        }
        __syncthreads();

        // gate phase: 1200 units
        for (int u = tid; u < 8 * HH; u += 640) {
            int s = u / HH, uu = u - s * HH;
            float gi = g[s][uu], gf = g[s][HH + uu], gg = g[s][2 * HH + uu], go = g[s][3 * HH + uu];
            float c = cst[s][uu];
            c = sigf(gf) * c + sigf(gi) * tanh_f(gg);
            float h = sigf(go) * tanh_f(c);
            cst[s][uu] = c;
            xh[s][DD + uu] = h;
            hmax[s][uu] = fmaxf(hmax[s][uu], h);
        }

        // write prefetched x for next step
        if (has_next) {
            int i0 = tid, i1 = tid + 640, i2 = tid + 1280, i3 = tid + 1920;
            int sA = i0 / DD, dA = i0 - sA * DD;
            int sB = i1 / DD, dB = i1 - sB * DD;
            int sC = i2 / DD, dC = i2 - sC * DD;
            xh[sA][dA] = pf0;
            xh[sB][dB] = pf1;
            xh[sC][dC] = pf2;
            if (i3 < 8 * DD) {
                int sD = i3 / DD, dD = i3 - sD * DD;
                xh[sD][dD] = pf3;
            }
        }
        __syncthreads();
    }

    for (int u = tid; u < 8 * HH; u += 640) {
        int s = u / HH, uu = u - s * HH;
        sent_emb[(size_t)(s0 + s) * DD + dir * HH + uu] = hmax[s][uu];
    }
}

// ---------------- stage-2 input projection ----------------
// grid 2048 = 1024 t x 2 dirs, block 256. xw2[dir][t][600]
__global__ void xw2_kernel(const float* __restrict__ sent_emb,
                           const float* __restrict__ Wih_f2, const float* __restrict__ bih_f2,
                           const float* __restrict__ bhh_f2,
                           const float* __restrict__ Wih_b2, const float* __restrict__ bih_b2,
                           const float* __restrict__ bhh_b2,
                           float* __restrict__ xw2) {
    __shared__ __align__(16) float xr[DD];
    const int t = blockIdx.x >> 1;
    const int dir = blockIdx.x & 1;
    const float* Wih2 = dir ? Wih_b2 : Wih_f2;
    const float* ba = dir ? bih_b2 : bih_f2;
    const float* bb = dir ? bhh_b2 : bhh_f2;
    for (int i = threadIdx.x; i < DD; i += 256) xr[i] = sent_emb[(size_t)t * DD + i];
    __syncthreads();
    for (int o = threadIdx.x; o < G4; o += 256) {
        float acc = ba[o] + bb[o];
        const float4* wr = (const float4*)(Wih2 + (size_t)o * DD);
        #pragma unroll 4
        for (int kc = 0; kc < DD / 4; ++kc) {
            float4 w4 = wr[kc];
            float4 xv = *((const float4*)&xr[kc * 4]);
            acc = fmaf(w4.x, xv.x, acc);
            acc = fmaf(w4.y, xv.y, acc);
            acc = fmaf(w4.z, xv.z, acc);
            acc = fmaf(w4.w, xv.w, acc);
        }
        xw2[((size_t)dir * SS + t) * G4 + o] = acc;
    }
}

// ---------------- sentence-level BiLSTM (stage 2) ----------------
// grid 2 (dir), block 640. Whh2 resident in registers; 1024 sequential steps.
__global__ __launch_bounds__(640, 1) void sent_lstm_kernel(
    const float* __restrict__ W2cat,    // [2][600][K2PAD]
    const float* __restrict__ xw2,      // [2][S][600]
    float* __restrict__ sent_out)       // [S][300]
{
    __shared__ __align__(16) float hl[K2PAD];
    __shared__ __align__(16) float g[G4];
    const int dir = blockIdx.x;
    const int tid = threadIdx.x;

    float4 wv[K2PAD / 4];
    if (tid < G4) {
        const float4* wr = (const float4*)(W2cat + ((size_t)dir * G4 + tid) * K2PAD);
        #pragma unroll
        for (int j = 0; j < K2PAD / 4; ++j) wv[j] = wr[j];
    }
    for (int i = tid; i < K2PAD; i += 640) hl[i] = 0.0f;
    float c = 0.0f;  // owned by tid < 150
    __syncthreads();

    for (int st = 0; st < SS; ++st) {
        const int tt = dir ? (SS - 1 - st) : st;
        if (tid < G4) {
            float acc = xw2[((size_t)dir * SS + tt) * G4 + tid];
            float a0 = 0.f, a1 = 0.f, a2 = 0.f, a3 = 0.f;
            #pragma unroll
            for (int j = 0; j < K2PAD / 4; ++j) {
                float4 h4 = *((const float4*)&hl[j * 4]);
                a0 = fmaf(wv[j].x, h4.x, a0);
                a1 = fmaf(wv[j].y, h4.y, a1);
                a2 = fmaf(wv[j].z, h4.z, a2);
                a3 = fmaf(wv[j].w, h4.w, a3);
            }
            g[tid] = acc + ((a0 + a1) + (a2 + a3));
        }
        __syncthreads();
        if (tid < HH) {
            float gi = g[tid], gf = g[HH + tid], gg = g[2 * HH + tid], go = g[3 * HH + tid];
            c = sigf(gf) * c + sigf(gi) * tanh_f(gg);
            float h = sigf(go) * tanh_f(c);
            hl[tid] = h;
            sent_out[(size_t)tt * DD + dir * HH + tid] = h;
        }
        __syncthreads();
    }
}

// ---------------- classification + loss ----------------
// grid 1024 (one wave per sentence)
__global__ void loss_kernel(const float* __restrict__ sent_out,
                            const int* __restrict__ gold,
                            const float* __restrict__ W_out, const float* __restrict__ b_out,
                            const float* __restrict__ last_rep,
                            float* __restrict__ d_out, float* __restrict__ loss_arr) {
    const int t = blockIdx.x;
    const int lane = threadIdx.x;
    const float* a = sent_out + (size_t)t * DD;

    float pl[CLS];
    #pragma unroll
    for (int j = 0; j < CLS; ++j) pl[j] = 0.0f;
    float na2 = 0.0f;
    for (int k = lane; k < DD; k += 64) {
        float av = a[k];
        na2 = fmaf(av, av, na2);
        #pragma unroll
        for (int j = 0; j < CLS; ++j) pl[j] = fmaf(av, W_out[j * DD + k], pl[j]);
    }
    #pragma unroll
    for (int off = 32; off > 0; off >>= 1) {
        na2 += __shfl_down(na2, off);
        #pragma unroll
        for (int j = 0; j < CLS; ++j) pl[j] += __shfl_down(pl[j], off);
    }

    int pre = 0;
    float nll = 0.0f, nrm_a = 1.0f;
    if (lane == 0) {
        float lg[CLS];
        float mx = -INFINITY;
        #pragma unroll
        for (int j = 0; j < CLS; ++j) {
            lg[j] = pl[j] + b_out[j];
            if (lg[j] > mx) mx = lg[j];
        }
        pre = 0;
        float bst = lg[0];
        #pragma unroll
        for (int j = 1; j < CLS; ++j) {       // first-max semantics (strict >)
            if (lg[j] > bst) { bst = lg[j]; pre = j; }
        }
        float se = 0.0f;
        #pragma unroll
        for (int j = 0; j < CLS; ++j) se += expf(lg[j] - mx);
        float lse = logf(se);
        nll = -(lg[gold[t]] - mx - lse);
        nrm_a = fmaxf(sqrtf(na2), 1e-8f);
    }
    pre = __shfl(pre, 0);

    const float* lr = last_rep + (size_t)pre * DD;
    float dp = 0.0f, nb2 = 0.0f;
    for (int k = lane; k < DD; k += 64) {
        float bv = lr[k];
        dp = fmaf(a[k], bv, dp);
        nb2 = fmaf(bv, bv, nb2);
    }
    #pragma unroll
    for (int off = 32; off > 0; off >>= 1) {
        dp += __shfl_down(dp, off);
        nb2 += __shfl_down(nb2, off);
    }
    if (lane == 0) {
        float nb = fmaxf(sqrtf(nb2), 1e-8f);
        float sim = dp / (nrm_a * nb);
        float lt = nll + ((pre != gold[t]) ? sim : 0.0f);
        loss_arr[t] = lt;
        d_out[t] = (float)pre;
    }
}

__global__ void reduce_loss_kernel(const float* __restrict__ loss_arr, float* __restrict__ out_loss) {
    __shared__ float sm[256];
    float s = 0.0f;
    for (int i = threadIdx.x; i < SS; i += 256) s += loss_arr[i];
    sm[threadIdx.x] = s;
    __syncthreads();
    for (int stp = 128; stp > 0; stp >>= 1) {
        if (threadIdx.x < stp) sm[threadIdx.x] += sm[threadIdx.x + stp];
        __syncthreads();
    }
    if (threadIdx.x == 0) out_loss[0] = sm[0];
}

extern "C" void kernel_launch(void* const* d_in, const int* in_sizes, int n_in,
                              void* d_out, int out_size, void* d_ws, size_t ws_size,
                              hipStream_t stream) {
    const float* x       = (const float*)d_in[0];
    const int*   gold    = (const int*)d_in[1];
    const float* Wih_f1  = (const float*)d_in[2];
    const float* Whh_f1  = (const float*)d_in[3];
    const float* bih_f1  = (const float*)d_in[4];
    const float* bhh_f1  = (const float*)d_in[5];
    const float* Wih_b1  = (const float*)d_in[6];
    const float* Whh_b1  = (const float*)d_in[7];
    const float* bih_b1  = (const float*)d_in[8];
    const float* bhh_b1  = (const float*)d_in[9];
    const float* Wih_f2  = (const float*)d_in[10];
    const float* Whh_f2  = (const float*)d_in[11];
    const float* bih_f2  = (const float*)d_in[12];
    const float* bhh_f2  = (const float*)d_in[13];
    const float* Wih_b2  = (const float*)d_in[14];
    const float* Whh_b2  = (const float*)d_in[15];
    const float* bih_b2  = (const float*)d_in[16];
    const float* bhh_b2  = (const float*)d_in[17];
    const float* W_out   = (const float*)d_in[18];
    const float* b_out   = (const float*)d_in[19];
    const float* last_rep= (const float*)d_in[20];

    float* ws = (float*)d_ws;
    float* Wcat     = ws;                         // 2*600*456   = 547200
    float* W2cat    = Wcat + 2 * G4 * KPAD;       // 2*600*152   = 182400
    float* sent_emb = W2cat + 2 * G4 * K2PAD;     // 1024*300    = 307200
    float* xw2      = sent_emb + SS * DD;         // 2*1024*600  = 1228800
    float* sent_out = xw2 + 2 * SS * G4;          // 1024*300    = 307200
    float* loss_arr = sent_out + SS * DD;         // 1024
    // total ~10.3 MB of workspace

    pack1_kernel<<<(2 * G4 * KPAD + 255) / 256, 256, 0, stream>>>(Wih_f1, Whh_f1, Wih_b1, Whh_b1, Wcat);
    pack2_kernel<<<(2 * G4 * K2PAD + 255) / 256, 256, 0, stream>>>(Whh_f2, Whh_b2, W2cat);
    word_lstm_kernel<<<256, 640, 0, stream>>>(x, Wcat, bih_f1, bhh_f1, bih_b1, bhh_b1, sent_emb);
    xw2_kernel<<<2048, 256, 0, stream>>>(sent_emb, Wih_f2, bih_f2, bhh_f2, Wih_b2, bih_b2, bhh_b2, xw2);
    sent_lstm_kernel<<<2, 640, 0, stream>>>(W2cat, xw2, sent_out);
    loss_kernel<<<1024, 64, 0, stream>>>(sent_out, gold, W_out, b_out, last_rep, (float*)d_out, loss_arr);
    reduce_loss_kernel<<<1, 256, 0, stream>>>(loss_arr, (float*)d_out + SS);
}